// Round 7
// baseline (40.747 us; speedup 1.0000x reference)
//
#include <hip/hip_runtime.h>
#include <math.h>

// ---------------- problem constants ----------------
#define NROWS 32768   // B*T independent rows (alpha=exp(-50): scan decouples, verified R1)
#define NK 256        // IN_F
#define NF 256        // F
#define NT_SEQ 256    // T
#define MTILE 64      // rows per block in the GEMM kernel
#define TAU 5e-4f     // fp16-split vs fp64 ambiguity band (validated R5/R6: absmax 0.0)

// Verified facts (R1/R3/R5/R6, absmax == 0.0):
//  * v_mem(t) == cur(t) exactly in the reference's own arithmetic.
//  * LN of binary s collapses: mu = k/256 exact, var = mu(1-mu).
//  * fp64 dot reproduces the np reference's spike decisions exactly.
//  * MFMA fragment mapping (A: row=lane&15, k=(lane>>4)*8+j; B: col=lane&15;
//    C/D: col=lane&15, row=(lane>>4)*4+reg) correct.
//  * fp16 2+2 split (a ~ ah + al/2048, W*16 ~ b1 + b2/2048), 3 MFMA products,
//    TAU=5e-4 recheck band: exact.
// R7: split into GEMM-kernel (bits+stats to ws) and streaming LN kernel,
// removing the 32MB write burst + LN reads from the GEMM blocks' critical path.

typedef __attribute__((ext_vector_type(4))) float f32x4;
typedef __attribute__((ext_vector_type(8))) _Float16 f16x8;

#define WT_SHORTS  131072                 // 2 comps x 65536 shorts = 256 KB
#define BITS_OFF   (WT_SHORTS * 2)        // byte offset of bits[] in ws
#define STATS_OFF  (BITS_OFF + NROWS * 32)// byte offset of stats[] in ws

__device__ __forceinline__ unsigned short f16_bits(float x) {
    return __builtin_bit_cast(unsigned short, (_Float16)x);   // RNE cvt
}

// ---- k0: split W*16 into 2 fp16 comps, MFMA-B-fragment order ----
// wt[comp][ks][chunk][col][j] shorts; comp stride 65536, ks 8192, chunk 2048.
__global__ void split_w(const float* __restrict__ W, unsigned short* __restrict__ wt) {
    const int k = blockIdx.x;       // 0..255
    const int col = threadIdx.x;    // 0..255
    const float w16 = W[k * NF + col] * 16.0f;     // exact scale by 2^4
    const _Float16 h1 = (_Float16)w16;             // RNE
    const float r = (w16 - (float)h1) * 2048.0f;   // exact (Sterbenz; *2^11)
    const _Float16 h2 = (_Float16)r;               // RNE
    const int ks = k >> 5, chunk = (k >> 3) & 3, j = k & 7;
    const int base = ((ks * 4 + chunk) * 2048) + col * 8 + j;
    wt[base] = __builtin_bit_cast(unsigned short, h1);
    wt[base + 65536] = __builtin_bit_cast(unsigned short, h2);
}

// ---- k1: split-GEMM + spike + exact recheck -> packed bits + per-row stats ----
__global__ __launch_bounds__(512, 4)
void lif_gemm(const float* __restrict__ spikes,
              const float* __restrict__ W,
              const float* __restrict__ bias,
              const unsigned short* __restrict__ wt,
              unsigned int* __restrict__ bitsg,     // [NROWS][8]
              float2* __restrict__ stats)           // [NROWS] (mu, rinv)
{
    // A panel: 2 comps x 64 rows x 256 k, row stride 264 halfs (528 B ->
    // frag-read banks 4r mod 32: 2-way = free).
    __shared__ __align__(16) short alds[2][MTILE][264];   // 67.6 KB
    __shared__ unsigned int bits[MTILE][8];               // 256-bit row masks
    __shared__ unsigned int elist[96];                    // in-band worklist
    __shared__ int ecnt;

    const int tid = threadIdx.x;
    const int lane = tid & 63;
    const int wid = tid >> 6;            // 0..7: cols [wid*32, +32)
    const int row0 = blockIdx.x * MTILE;

    if (tid == 0) ecnt = 0;

    // ---- stage full A panel, split to fp16 pairs (one barrier total) ----
    #pragma unroll
    for (int it = 0; it < 8; ++it) {
        const int idx = it * 2048 + tid * 4;
        const int r = idx >> 8, c = idx & 255;
        const float4 v = *reinterpret_cast<const float4*>(
            spikes + (size_t)(row0 + r) * NK + c);
        unsigned short h[4], l[4];
        const float fv[4] = {v.x, v.y, v.z, v.w};
        #pragma unroll
        for (int e = 0; e < 4; ++e) {
            h[e] = f16_bits(fv[e]);
            const float hf = (float)__builtin_bit_cast(_Float16, h[e]);
            l[e] = f16_bits((fv[e] - hf) * 2048.0f);
        }
        *(uint2*)&alds[0][r][c] = make_uint2((unsigned int)h[0] | ((unsigned int)h[1] << 16),
                                             (unsigned int)h[2] | ((unsigned int)h[3] << 16));
        *(uint2*)&alds[1][r][c] = make_uint2((unsigned int)l[0] | ((unsigned int)l[1] << 16),
                                             (unsigned int)l[2] | ((unsigned int)l[3] << 16));
    }
    __syncthreads();

    // ---- barrier-free K loop: 8 steps x 24 MFMA (4 mt x 2 nt x 3 products) ----
    f32x4 acc0[4][2], acc1[4][2];
    {
        const f32x4 z = {0.f, 0.f, 0.f, 0.f};
        #pragma unroll
        for (int mt = 0; mt < 4; ++mt)
            #pragma unroll
            for (int nt = 0; nt < 2; ++nt) { acc0[mt][nt] = z; acc1[mt][nt] = z; }
    }
    const int a_off = (lane & 15) * 264 + (lane >> 4) * 8;       // halfs
    const int b_off = (lane >> 4) * 2048 + (wid * 32 + (lane & 15)) * 8;
    const short* alds_flat = &alds[0][0][0];

    #pragma unroll 2
    for (int ks = 0; ks < 8; ++ks) {
        f16x8 bf[2][2];
        #pragma unroll
        for (int c = 0; c < 2; ++c)
            #pragma unroll
            for (int nt = 0; nt < 2; ++nt)
                bf[c][nt] = *reinterpret_cast<const f16x8*>(
                    wt + c * 65536 + ks * 8192 + b_off + nt * 128);
        f16x8 ah[4], al[4];
        #pragma unroll
        for (int mt = 0; mt < 4; ++mt) {
            ah[mt] = *reinterpret_cast<const f16x8*>(
                alds_flat + (mt * 16) * 264 + ks * 32 + a_off);
            al[mt] = *reinterpret_cast<const f16x8*>(
                alds_flat + 16896 + (mt * 16) * 264 + ks * 32 + a_off);
        }
        #pragma unroll
        for (int mt = 0; mt < 4; ++mt)
            #pragma unroll
            for (int nt = 0; nt < 2; ++nt) {
                acc0[mt][nt] = __builtin_amdgcn_mfma_f32_16x16x32_f16(ah[mt], bf[0][nt], acc0[mt][nt], 0, 0, 0);
                acc1[mt][nt] = __builtin_amdgcn_mfma_f32_16x16x32_f16(ah[mt], bf[1][nt], acc1[mt][nt], 0, 0, 0);
                acc1[mt][nt] = __builtin_amdgcn_mfma_f32_16x16x32_f16(al[mt], bf[0][nt], acc1[mt][nt], 0, 0, 0);
            }
    }

    // ---- decisions; in-band elements -> worklist ----
    unsigned int smask[4] = {0u, 0u, 0u, 0u};   // bit nt*4+reg
    #pragma unroll
    for (int mt = 0; mt < 4; ++mt)
        #pragma unroll
        for (int nt = 0; nt < 2; ++nt) {
            const int gcol = wid * 32 + nt * 16 + (lane & 15);
            const float bv = bias[gcol];
            #pragma unroll
            for (int reg = 0; reg < 4; ++reg) {
                // v = (acc0 + acc1/2048) / 16 + bias
                const float v = fmaf(acc1[mt][nt][reg], 4.8828125e-4f,
                                     acc0[mt][nt][reg]) * 0.0625f + bv;
                if ((v - 0.5f) > 0.0f) smask[mt] |= 1u << (nt * 4 + reg);
                if (__builtin_expect(fabsf(v - 0.5f) < TAU, 0)) {
                    const int rl = mt * 16 + (lane >> 4) * 4 + reg;
                    const int ei = atomicAdd(&ecnt, 1);
                    if (ei < 96) elist[ei] = (unsigned int)((rl << 8) | gcol);
                }
            }
        }

    // ---- assemble row masks ----
    #pragma unroll
    for (int mt = 0; mt < 4; ++mt)
        #pragma unroll
        for (int reg = 0; reg < 4; ++reg) {
            const unsigned long long m0 = __ballot((smask[mt] >> (reg)) & 1u);
            const unsigned long long m1 = __ballot((smask[mt] >> (4 + reg)) & 1u);
            if (lane < 4) {
                const int g = lane;
                const unsigned int w =
                    (unsigned int)((m0 >> (g * 16)) & 0xFFFFull) |
                    ((unsigned int)((m1 >> (g * 16)) & 0xFFFFull) << 16);
                bits[mt * 16 + g * 4 + reg][wid] = w;
            }
        }
    __syncthreads();

    // ---- exact fp64 recheck of in-band elements (wave-parallel, rare) ----
    const int ne = min(ecnt, 96);
    for (int e = wid; e < ne; e += 8) {
        const unsigned int pk = elist[e];
        const int rl = (int)(pk >> 8), gcol = (int)(pk & 255u);
        const float* sr = spikes + (size_t)(row0 + rl) * NK;
        const float* wc = W + gcol;
        const int k0 = lane * 4;
        const double p0 = (double)sr[k0 + 0] * (double)wc[(size_t)(k0 + 0) * NF];
        const double p1 = (double)sr[k0 + 1] * (double)wc[(size_t)(k0 + 1) * NF];
        const double p2 = (double)sr[k0 + 2] * (double)wc[(size_t)(k0 + 2) * NF];
        const double p3 = (double)sr[k0 + 3] * (double)wc[(size_t)(k0 + 3) * NF];
        double pl = (p0 + p1) + (p2 + p3);
        #pragma unroll
        for (int off = 32; off > 0; off >>= 1) pl += __shfl_down(pl, off);
        if (lane == 0) {
            const double vex = pl + (double)bias[gcol];
            const bool sex = (vex - 0.5) > 0.0;
            const bool spv = (bits[rl][gcol >> 5] >> (gcol & 31)) & 1u;
            if (sex != spv) atomicXor(&bits[rl][gcol >> 5], 1u << (gcol & 31));
        }
    }
    __syncthreads();

    // ---- per-row stats (identical double math to R1..R6) + bits writeback ----
    if (tid < MTILE) {
        int kc = 0;
        #pragma unroll
        for (int w = 0; w < 8; ++w) kc += __popc(bits[tid][w]);
        const double mu = (double)kc * (1.0 / 256.0);
        const double var = mu * (1.0 - mu);
        stats[row0 + tid] = make_float2((float)mu, (float)(1.0 / sqrt(var + 1e-6)));
    }
    const int rr = tid >> 3, w = tid & 7;     // 512 threads cover 64 rows x 8 words
    bitsg[(size_t)(row0 + rr) * 8 + w] = bits[rr][w];
}

// ---- k2: streaming LN epilogue (pure memory-bound) ----
__global__ __launch_bounds__(256)
void lif_ln(const unsigned int* __restrict__ bitsg,
            const float2* __restrict__ stats,
            const float* __restrict__ ln_scale,
            const float* __restrict__ ln_bias,
            float* __restrict__ out)
{
    const int tid = threadIdx.x;
    const int lane = tid & 63;
    const int row = blockIdx.x * 4 + (tid >> 6);   // 4 rows per block
    const int t = row & (NT_SEQ - 1);
    const float2 st = stats[row];                  // (mu, rinv)
    const unsigned int wb = bitsg[(size_t)row * 8 + (lane >> 3)];
    const int f = lane * 4;
    const int sh = f & 31;
    const float4 g4 = *reinterpret_cast<const float4*>(&ln_scale[t * NF + f]);
    const float4 b4 = *reinterpret_cast<const float4*>(&ln_bias[t * NF + f]);
    const float muf = st.x, rinv = st.y;
    float4 o;
    const float s0 = ((wb >> (sh + 0)) & 1u) ? 1.0f : 0.0f;
    const float s1 = ((wb >> (sh + 1)) & 1u) ? 1.0f : 0.0f;
    const float s2 = ((wb >> (sh + 2)) & 1u) ? 1.0f : 0.0f;
    const float s3 = ((wb >> (sh + 3)) & 1u) ? 1.0f : 0.0f;
    o.x = (s0 - muf) * rinv * g4.x + b4.x;
    o.y = (s1 - muf) * rinv * g4.y + b4.y;
    o.z = (s2 - muf) * rinv * g4.z + b4.z;
    o.w = (s3 - muf) * rinv * g4.w + b4.w;
    *reinterpret_cast<float4*>(&out[(size_t)row * NF + f]) = o;
}

extern "C" void kernel_launch(void* const* d_in, const int* in_sizes, int n_in,
                              void* d_out, int out_size, void* d_ws, size_t ws_size,
                              hipStream_t stream) {
    const float* spikes   = (const float*)d_in[0];
    const float* W        = (const float*)d_in[1];
    const float* bias     = (const float*)d_in[2];
    const float* ln_scale = (const float*)d_in[3];
    const float* ln_bias  = (const float*)d_in[4];
    float* out = (float*)d_out;

    unsigned short* wt = (unsigned short*)d_ws;                         // 256 KB
    unsigned int* bitsg = (unsigned int*)((char*)d_ws + BITS_OFF);      // 1 MB
    float2* stats = (float2*)((char*)d_ws + STATS_OFF);                 // 256 KB

    split_w<<<dim3(256), dim3(256), 0, stream>>>(W, wt);
    lif_gemm<<<dim3(NROWS / MTILE), dim3(512), 0, stream>>>(
        spikes, W, bias, wt, bitsg, stats);
    lif_ln<<<dim3(NROWS / 4), dim3(256), 0, stream>>>(
        bitsg, stats, ln_scale, ln_bias, out);
}

// Round 8
// 36.474 us; speedup vs baseline: 1.1172x; 1.1172x over previous
//
#include <hip/hip_runtime.h>
#include <math.h>

// ---------------- problem constants ----------------
#define NROWS 32768   // B*T independent rows (alpha=exp(-50): scan decouples, verified R1)
#define NK 256        // IN_F
#define NF 256        // F
#define NT_SEQ 256    // T
#define MTILE 64      // rows per block
#define TAU 5e-4f     // fp16-split vs fp64 ambiguity band (validated R5/R6: absmax 0.0)

// Verified facts (R1/R3/R5/R6, absmax == 0.0):
//  * v_mem(t) == cur(t) exactly in the reference's own arithmetic.
//  * LN of binary s collapses: mu = k/256 exact, var = mu(1-mu).
//  * fp64 dot reproduces the np reference's spike decisions exactly.
//  * MFMA fragment mapping (A: row=lane&15, k=(lane>>4)*8+j; B: col=lane&15;
//    C/D: col=lane&15, row=(lane>>4)*4+reg) correct.
//  * fp16 2+2 split (a ~ ah + al/2048, W*16 ~ b1 + b2/2048), 3 MFMA products,
//    TAU=5e-4 recheck band: exact.
// R8: monolith (R7 split regressed) + 4-chunk software-pipelined staging:
// issue chunk c+1 global loads -> MFMA chunk c -> cvt+write c+1 -> barrier.
// Disjoint LDS columns per chunk => no double buffer needed.

typedef __attribute__((ext_vector_type(4))) float f32x4;
typedef __attribute__((ext_vector_type(8))) _Float16 f16x8;

__device__ __forceinline__ unsigned short f16_bits(float x) {
    return __builtin_bit_cast(unsigned short, (_Float16)x);   // RNE cvt
}

// ---- k0: split W*16 into 2 fp16 comps, MFMA-B-fragment order ----
// wt[comp][ks][chunk][col][j] shorts; comp stride 65536, ks 8192, chunk 2048.
__global__ void split_w(const float* __restrict__ W, unsigned short* __restrict__ wt) {
    const int k = blockIdx.x;       // 0..255
    const int col = threadIdx.x;    // 0..255
    const float w16 = W[k * NF + col] * 16.0f;     // exact scale by 2^4
    const _Float16 h1 = (_Float16)w16;             // RNE
    const float r = (w16 - (float)h1) * 2048.0f;   // exact (Sterbenz; *2^11)
    const _Float16 h2 = (_Float16)r;               // RNE
    const int ks = k >> 5, chunk = (k >> 3) & 3, j = k & 7;
    const int base = ((ks * 4 + chunk) * 2048) + col * 8 + j;
    wt[base] = __builtin_bit_cast(unsigned short, h1);
    wt[base + 65536] = __builtin_bit_cast(unsigned short, h2);
}

// ---- k1: pipelined split-GEMM + spike + exact recheck + closed-form LN ----
__global__ __launch_bounds__(512, 4)
void lif_main(const float* __restrict__ spikes,
              const float* __restrict__ W,
              const float* __restrict__ bias,
              const float* __restrict__ ln_scale,
              const float* __restrict__ ln_bias,
              const unsigned short* __restrict__ wt,
              float* __restrict__ out)
{
    // A panel: 2 comps x 64 rows x 256 k, row stride 264 halfs (528 B ->
    // frag-read banks 4r mod 32: 2-way = free). comp1 offset 16896 shorts.
    __shared__ __align__(16) short alds[2][MTILE][264];   // 67.6 KB
    __shared__ unsigned int bits[MTILE][8];               // 256-bit row masks
    __shared__ float rinv_s[MTILE], mu_s[MTILE];
    __shared__ unsigned int elist[96];                    // in-band worklist
    __shared__ int ecnt;

    const int tid = threadIdx.x;
    const int lane = tid & 63;
    const int wid = tid >> 6;            // 0..7: cols [wid*32, +32)
    const int row0 = blockIdx.x * MTILE;

    if (tid == 0) ecnt = 0;

    // staging map (per chunk, 2 float4 per thread):
    //  it in {0,1}: flat = it*512 + tid; r = flat>>4; c4 = flat&15;
    //  col = chunk*64 + c4*4
    const int st_r0 = (tid) >> 4,          st_c0 = (tid & 15) * 4;
    const int st_r1 = (512 + tid) >> 4,    st_c1 = (tid & 15) * 4;   // r0+32

    const short* alds_flat = &alds[0][0][0];
    short* alds_w = &alds[0][0][0];

    // ---- helpers as lambdas (compile-time unrolled) ----
    auto cvt_write = [&](int chunk, const float4& va, const float4& vb) {
        const float fv0[4] = {va.x, va.y, va.z, va.w};
        const float fv1[4] = {vb.x, vb.y, vb.z, vb.w};
        unsigned short h0[4], l0[4], h1[4], l1[4];
        #pragma unroll
        for (int e = 0; e < 4; ++e) {
            h0[e] = f16_bits(fv0[e]);
            const float hf0 = (float)__builtin_bit_cast(_Float16, h0[e]);
            l0[e] = f16_bits((fv0[e] - hf0) * 2048.0f);
            h1[e] = f16_bits(fv1[e]);
            const float hf1 = (float)__builtin_bit_cast(_Float16, h1[e]);
            l1[e] = f16_bits((fv1[e] - hf1) * 2048.0f);
        }
        const int o0 = st_r0 * 264 + chunk * 64 + st_c0;
        const int o1 = st_r1 * 264 + chunk * 64 + st_c1;
        *(uint2*)&alds_w[o0] = make_uint2((unsigned int)h0[0] | ((unsigned int)h0[1] << 16),
                                          (unsigned int)h0[2] | ((unsigned int)h0[3] << 16));
        *(uint2*)&alds_w[16896 + o0] = make_uint2((unsigned int)l0[0] | ((unsigned int)l0[1] << 16),
                                                  (unsigned int)l0[2] | ((unsigned int)l0[3] << 16));
        *(uint2*)&alds_w[o1] = make_uint2((unsigned int)h1[0] | ((unsigned int)h1[1] << 16),
                                          (unsigned int)h1[2] | ((unsigned int)h1[3] << 16));
        *(uint2*)&alds_w[16896 + o1] = make_uint2((unsigned int)l1[0] | ((unsigned int)l1[1] << 16),
                                                  (unsigned int)l1[2] | ((unsigned int)l1[3] << 16));
    };

    // ---- accumulators ----
    f32x4 acc0[4][2], acc1[4][2];
    {
        const f32x4 z = {0.f, 0.f, 0.f, 0.f};
        #pragma unroll
        for (int mt = 0; mt < 4; ++mt)
            #pragma unroll
            for (int nt = 0; nt < 2; ++nt) { acc0[mt][nt] = z; acc1[mt][nt] = z; }
    }
    const int a_off = (lane & 15) * 264 + (lane >> 4) * 8;       // halfs
    const int b_off = (lane >> 4) * 2048 + (wid * 32 + (lane & 15)) * 8;

    // ---- prologue: stage chunk 0 ----
    {
        const float4 va = *reinterpret_cast<const float4*>(
            spikes + (size_t)(row0 + st_r0) * NK + st_c0);
        const float4 vb = *reinterpret_cast<const float4*>(
            spikes + (size_t)(row0 + st_r1) * NK + st_c1);
        cvt_write(0, va, vb);
    }
    __syncthreads();

    // ---- pipelined chunk loop: 4 chunks x 2 ks ----
    #pragma unroll
    for (int c = 0; c < 4; ++c) {
        float4 va, vb;
        if (c < 3) {   // issue next-chunk loads (stay in flight through MFMAs)
            const int col_a = (c + 1) * 64 + st_c0;
            const int col_b = (c + 1) * 64 + st_c1;
            va = *reinterpret_cast<const float4*>(
                spikes + (size_t)(row0 + st_r0) * NK + col_a);
            vb = *reinterpret_cast<const float4*>(
                spikes + (size_t)(row0 + st_r1) * NK + col_b);
        }

        #pragma unroll
        for (int kk = 0; kk < 2; ++kk) {
            const int ks = c * 2 + kk;
            f16x8 bf[2][2];
            #pragma unroll
            for (int cc = 0; cc < 2; ++cc)
                #pragma unroll
                for (int nt = 0; nt < 2; ++nt)
                    bf[cc][nt] = *reinterpret_cast<const f16x8*>(
                        wt + cc * 65536 + ks * 8192 + b_off + nt * 128);
            f16x8 ah[4], al[4];
            #pragma unroll
            for (int mt = 0; mt < 4; ++mt) {
                ah[mt] = *reinterpret_cast<const f16x8*>(
                    alds_flat + (mt * 16) * 264 + ks * 32 + a_off);
                al[mt] = *reinterpret_cast<const f16x8*>(
                    alds_flat + 16896 + (mt * 16) * 264 + ks * 32 + a_off);
            }
            #pragma unroll
            for (int mt = 0; mt < 4; ++mt)
                #pragma unroll
                for (int nt = 0; nt < 2; ++nt) {
                    acc0[mt][nt] = __builtin_amdgcn_mfma_f32_16x16x32_f16(ah[mt], bf[0][nt], acc0[mt][nt], 0, 0, 0);
                    acc1[mt][nt] = __builtin_amdgcn_mfma_f32_16x16x32_f16(ah[mt], bf[1][nt], acc1[mt][nt], 0, 0, 0);
                    acc1[mt][nt] = __builtin_amdgcn_mfma_f32_16x16x32_f16(al[mt], bf[0][nt], acc1[mt][nt], 0, 0, 0);
                }
        }

        if (c < 3) cvt_write(c + 1, va, vb);
        __syncthreads();
    }

    // ---- decisions; in-band elements -> worklist ----
    unsigned int smask[4] = {0u, 0u, 0u, 0u};   // bit nt*4+reg
    #pragma unroll
    for (int mt = 0; mt < 4; ++mt)
        #pragma unroll
        for (int nt = 0; nt < 2; ++nt) {
            const int gcol = wid * 32 + nt * 16 + (lane & 15);
            const float bv = bias[gcol];
            #pragma unroll
            for (int reg = 0; reg < 4; ++reg) {
                // v = (acc0 + acc1/2048) / 16 + bias
                const float v = fmaf(acc1[mt][nt][reg], 4.8828125e-4f,
                                     acc0[mt][nt][reg]) * 0.0625f + bv;
                if ((v - 0.5f) > 0.0f) smask[mt] |= 1u << (nt * 4 + reg);
                if (__builtin_expect(fabsf(v - 0.5f) < TAU, 0)) {
                    const int rl = mt * 16 + (lane >> 4) * 4 + reg;
                    const int ei = atomicAdd(&ecnt, 1);
                    if (ei < 96) elist[ei] = (unsigned int)((rl << 8) | gcol);
                }
            }
        }

    // ---- assemble row masks ----
    #pragma unroll
    for (int mt = 0; mt < 4; ++mt)
        #pragma unroll
        for (int reg = 0; reg < 4; ++reg) {
            const unsigned long long m0 = __ballot((smask[mt] >> (reg)) & 1u);
            const unsigned long long m1 = __ballot((smask[mt] >> (4 + reg)) & 1u);
            if (lane < 4) {
                const int g = lane;
                const unsigned int w =
                    (unsigned int)((m0 >> (g * 16)) & 0xFFFFull) |
                    ((unsigned int)((m1 >> (g * 16)) & 0xFFFFull) << 16);
                bits[mt * 16 + g * 4 + reg][wid] = w;
            }
        }
    __syncthreads();

    // ---- exact fp64 recheck of in-band elements (wave-parallel, rare) ----
    const int ne = min(ecnt, 96);
    for (int e = wid; e < ne; e += 8) {
        const unsigned int pk = elist[e];
        const int rl = (int)(pk >> 8), gcol = (int)(pk & 255u);
        const float* sr = spikes + (size_t)(row0 + rl) * NK;
        const float* wc = W + gcol;
        const int k0 = lane * 4;
        const double p0 = (double)sr[k0 + 0] * (double)wc[(size_t)(k0 + 0) * NF];
        const double p1 = (double)sr[k0 + 1] * (double)wc[(size_t)(k0 + 1) * NF];
        const double p2 = (double)sr[k0 + 2] * (double)wc[(size_t)(k0 + 2) * NF];
        const double p3 = (double)sr[k0 + 3] * (double)wc[(size_t)(k0 + 3) * NF];
        double pl = (p0 + p1) + (p2 + p3);
        #pragma unroll
        for (int off = 32; off > 0; off >>= 1) pl += __shfl_down(pl, off);
        if (lane == 0) {
            const double vex = pl + (double)bias[gcol];
            const bool sex = (vex - 0.5) > 0.0;
            const bool spv = (bits[rl][gcol >> 5] >> (gcol & 31)) & 1u;
            if (sex != spv) atomicXor(&bits[rl][gcol >> 5], 1u << (gcol & 31));
        }
    }
    __syncthreads();

    // ---- per-row stats (identical double math to R1..R6) ----
    if (tid < MTILE) {
        int kc = 0;
        #pragma unroll
        for (int w = 0; w < 8; ++w) kc += __popc(bits[tid][w]);
        const double mu = (double)kc * (1.0 / 256.0);
        const double var = mu * (1.0 - mu);
        rinv_s[tid] = (float)(1.0 / sqrt(var + 1e-6));
        mu_s[tid] = (float)mu;
    }
    __syncthreads();

    // ---- LN epilogue + coalesced float4 store ----
    const int orow = tid >> 3;           // 0..63
    const int of0 = (tid & 7) * 4;       // 0..28
    const int grow = row0 + orow;
    const int t = grow & (NT_SEQ - 1);
    const float rinv = rinv_s[orow];
    const float muf = mu_s[orow];
    #pragma unroll
    for (int j = 0; j < 8; ++j) {
        const int f = of0 + j * 32;
        const unsigned int wb = bits[orow][j];   // f>>5 == j since of0 < 32
        const int sh = of0;
        const float4 g4 = *reinterpret_cast<const float4*>(&ln_scale[t * NF + f]);
        const float4 b4 = *reinterpret_cast<const float4*>(&ln_bias[t * NF + f]);
        float4 o;
        const float s0 = ((wb >> (sh + 0)) & 1u) ? 1.0f : 0.0f;
        const float s1 = ((wb >> (sh + 1)) & 1u) ? 1.0f : 0.0f;
        const float s2 = ((wb >> (sh + 2)) & 1u) ? 1.0f : 0.0f;
        const float s3 = ((wb >> (sh + 3)) & 1u) ? 1.0f : 0.0f;
        o.x = (s0 - muf) * rinv * g4.x + b4.x;
        o.y = (s1 - muf) * rinv * g4.y + b4.y;
        o.z = (s2 - muf) * rinv * g4.z + b4.z;
        o.w = (s3 - muf) * rinv * g4.w + b4.w;
        *reinterpret_cast<float4*>(&out[(size_t)grow * NF + f]) = o;
    }
}

extern "C" void kernel_launch(void* const* d_in, const int* in_sizes, int n_in,
                              void* d_out, int out_size, void* d_ws, size_t ws_size,
                              hipStream_t stream) {
    const float* spikes   = (const float*)d_in[0];
    const float* W        = (const float*)d_in[1];
    const float* bias     = (const float*)d_in[2];
    const float* ln_scale = (const float*)d_in[3];
    const float* ln_bias  = (const float*)d_in[4];
    float* out = (float*)d_out;
    unsigned short* wt = (unsigned short*)d_ws;   // 256 KB

    split_w<<<dim3(256), dim3(256), 0, stream>>>(W, wt);
    lif_main<<<dim3(NROWS / MTILE), dim3(512), 0, stream>>>(
        spikes, W, bias, ln_scale, ln_bias, wt, out);
}